// Round 7
// baseline (579.742 us; speedup 1.0000x reference)
//
#include <hip/hip_runtime.h>

// IcoPool: out[b,f,v] = mean_{k<7} x[b,f,idx[v,k]]
// x: (8, 64, 163842) f32, idx: (40962, 7) int32, out: (8, 64, 40962) f32
//
// v2-v6 history: interleaved slab (one random address serves many rows);
//   L2/L3 window blocking; 64B-entry quad-cooperative gathers; fp16 slab
//   (fills halved, absmax 0.0078 passes). Overhead model: total = ~305us
//   harness (incl 204us ws-poison fill) + kernels (~274us at v6).
// v7: pass2 merges each XCD's two groups into one block (idx + addr setup
//   amortized 2x, 14 line-fills in flight per lane vs 7). Pass1 reads 32B/lane
//   (2x dwordx4) with CPB=256 (half the blocks).

typedef float    f4 __attribute__((ext_vector_type(4)));
typedef float    f8 __attribute__((ext_vector_type(8)));
typedef _Float16 h8 __attribute__((ext_vector_type(8)));
typedef unsigned int u4 __attribute__((ext_vector_type(4)));

constexpr int B = 8, F = 64, V_IN = 163842, V_OUT = 40962, K = 7;
constexpr int ROWS = B * F;                        // 512
constexpr int RG   = 32;                           // rows per entry (64 B fp16)
constexpr int NG   = ROWS / RG;                    // 16 groups
constexpr int TPB  = 256;
constexpr int GPX  = NG / 8;                       // 2 groups per XCD
// pass 1
constexpr int CPB  = 256;                          // columns per block
constexpr int IBX  = (V_IN + CPB - 1) / CPB;       // 641
constexpr int LSH  = 34;                           // LDS halves per column (32+pad)
// pass 2
constexpr int VPB  = 64;                           // v per block (4 lanes each)
constexpr int VB   = (V_OUT + VPB - 1) / VPB;      // 641
constexpr int BLOCKS2 = 8 * VB;                    // 5128 (both groups per block)
constexpr size_t XH_BYTES = (size_t)NG * V_IN * 64; // 167.8 MB

// ---- pass 1: transpose-pack 32 f32 rows -> 64B fp16 entries, via LDS ----
__global__ __launch_bounds__(TPB) void icopool_pack_h(
    const float* __restrict__ x, u4* __restrict__ xH)
{
    __shared__ _Float16 tile[CPB * LSH];           // 17408 B
    const int g  = blockIdx.y;
    const int c0 = blockIdx.x * CPB;
    const int t  = threadIdx.x;
    const int r  = t >> 3;                         // 0..31
    const int ci = t & 7;

    const float* xr = x + (size_t)(g * RG + r) * V_IN;
    if (c0 + CPB <= V_IN) {
        #pragma unroll
        for (int it = 0; it < 4; ++it) {
            const int c8 = ci * 8 + it * 64;
            const f4 v0 = *(const f4*)(xr + c0 + c8);
            const f4 v1 = *(const f4*)(xr + c0 + c8 + 4);
            tile[(c8 + 0) * LSH + r] = (_Float16)v0.x;
            tile[(c8 + 1) * LSH + r] = (_Float16)v0.y;
            tile[(c8 + 2) * LSH + r] = (_Float16)v0.z;
            tile[(c8 + 3) * LSH + r] = (_Float16)v0.w;
            tile[(c8 + 4) * LSH + r] = (_Float16)v1.x;
            tile[(c8 + 5) * LSH + r] = (_Float16)v1.y;
            tile[(c8 + 6) * LSH + r] = (_Float16)v1.z;
            tile[(c8 + 7) * LSH + r] = (_Float16)v1.w;
        }
    } else {
        for (int it = 0; it < 4; ++it) {
            const int c8 = ci * 8 + it * 64;
            for (int jj = 0; jj < 8; ++jj) {
                const int c = c0 + c8 + jj;
                tile[(c8 + jj) * LSH + r] =
                    (c < V_IN) ? (_Float16)xr[c] : (_Float16)0.0f;
            }
        }
    }
    __syncthreads();

    const unsigned int* ld = (const unsigned int*)tile;  // dword view (17/col)
    u4* dst = xH + ((size_t)g * V_IN + c0) * 4;
    #pragma unroll
    for (int it = 0; it < 4; ++it) {
        const int c   = (t >> 2) + it * 64;        // 0..255
        const int sub = t & 3;
        if (c0 + c < V_IN) {
            u4 w;
            w.x = ld[c * 17 + sub * 4 + 0];
            w.y = ld[c * 17 + sub * 4 + 1];
            w.z = ld[c * 17 + sub * 4 + 2];
            w.w = ld[c * 17 + sub * 4 + 3];
            __builtin_nontemporal_store(w, dst + (size_t)c * 4 + sub);
        }
    }
}

// ---- pass 2: quad-cooperative fp16 gather, both XCD groups per block ----
// 4 lanes per v; lane sub loads 16B = rows sub*8..+7 of the 64B entry; quad's
// 4 loads merge into ONE 64B line request. 14 independent fills per lane.
__global__ __launch_bounds__(TPB) void icopool_gather_h2(
    const h8* __restrict__ xH,
    const int* __restrict__ nidx,
    float*     __restrict__ out)
{
    const int b   = blockIdx.x;
    const int xcd = b & 7;               // HW round-robin XCD assignment
    const int vb  = b >> 3;              // v-block
    const int sub = threadIdx.x & 3;
    const int lv  = threadIdx.x >> 2;    // 0..63
    const int v   = vb * VPB + lv;
    if (v >= V_OUT) return;
    const int g0  = xcd * GPX;

    const int base = v * K;
    const int i0 = nidx[base + 0];
    const int i1 = nidx[base + 1];
    const int i2 = nidx[base + 2];
    const int i3 = nidx[base + 3];
    const int i4 = nidx[base + 4];
    const int i5 = nidx[base + 5];
    const int i6 = nidx[base + 6];

    const h8* s0 = xH + ((size_t)g0 * V_IN) * 4 + sub;
    const h8* s1 = s0 + (size_t)V_IN * 4;

    const h8 a0 = s0[(size_t)i0 * 4];
    const h8 a1 = s0[(size_t)i1 * 4];
    const h8 a2 = s0[(size_t)i2 * 4];
    const h8 a3 = s0[(size_t)i3 * 4];
    const h8 a4 = s0[(size_t)i4 * 4];
    const h8 a5 = s0[(size_t)i5 * 4];
    const h8 a6 = s0[(size_t)i6 * 4];
    const h8 b0 = s1[(size_t)i0 * 4];
    const h8 b1 = s1[(size_t)i1 * 4];
    const h8 b2 = s1[(size_t)i2 * 4];
    const h8 b3 = s1[(size_t)i3 * 4];
    const h8 b4 = s1[(size_t)i4 * 4];
    const h8 b5 = s1[(size_t)i5 * 4];
    const h8 b6 = s1[(size_t)i6 * 4];

    f8 acc0 = __builtin_convertvector(a0, f8);
    acc0 += __builtin_convertvector(a1, f8);
    acc0 += __builtin_convertvector(a2, f8);
    acc0 += __builtin_convertvector(a3, f8);
    acc0 += __builtin_convertvector(a4, f8);
    acc0 += __builtin_convertvector(a5, f8);
    acc0 += __builtin_convertvector(a6, f8);
    acc0 *= (1.0f / 7.0f);
    f8 acc1 = __builtin_convertvector(b0, f8);
    acc1 += __builtin_convertvector(b1, f8);
    acc1 += __builtin_convertvector(b2, f8);
    acc1 += __builtin_convertvector(b3, f8);
    acc1 += __builtin_convertvector(b4, f8);
    acc1 += __builtin_convertvector(b5, f8);
    acc1 += __builtin_convertvector(b6, f8);
    acc1 *= (1.0f / 7.0f);

    float* o0 = out + (size_t)(g0 * RG + sub * 8) * V_OUT + v;
    float* o1 = o0 + (size_t)RG * V_OUT;
    #pragma unroll
    for (int rr = 0; rr < 8; ++rr) {
        __builtin_nontemporal_store(acc0[rr], o0 + (size_t)rr * V_OUT);
        __builtin_nontemporal_store(acc1[rr], o1 + (size_t)rr * V_OUT);
    }
}

// ---------------- fallback (v1): direct gather, no workspace ----------------
constexpr int RPB  = 2;
constexpr int RGS  = ROWS / RPB;
constexpr int RG_PER_XCD = RGS / 8;
constexpr int VB1  = (V_OUT + TPB - 1) / TPB;
constexpr int BLOCKS_V1  = RGS * VB1;

__global__ __launch_bounds__(TPB) void icopool_gather(
    const float* __restrict__ x,
    const int*   __restrict__ nidx,
    float*       __restrict__ out)
{
    const int b        = blockIdx.x;
    const int xcd      = b & 7;
    const int j        = b >> 3;
    const int rg_local = j / VB1;
    const int vb       = j % VB1;
    const int rg       = xcd * RG_PER_XCD + rg_local;
    const int r0       = rg * RPB;

    const int v = vb * TPB + threadIdx.x;
    if (v >= V_OUT) return;

    const int base = v * K;
    const int i0 = nidx[base + 0];
    const int i1 = nidx[base + 1];
    const int i2 = nidx[base + 2];
    const int i3 = nidx[base + 3];
    const int i4 = nidx[base + 4];
    const int i5 = nidx[base + 5];
    const int i6 = nidx[base + 6];

    #pragma unroll
    for (int r = 0; r < RPB; ++r) {
        const float* xr = x + (size_t)(r0 + r) * V_IN;
        float sum = xr[i0] + xr[i1] + xr[i2] + xr[i3] + xr[i4] + xr[i5] + xr[i6];
        __builtin_nontemporal_store(sum * (1.0f / 7.0f),
                                    out + (size_t)(r0 + r) * V_OUT + v);
    }
}

extern "C" void kernel_launch(void* const* d_in, const int* in_sizes, int n_in,
                              void* d_out, int out_size, void* d_ws, size_t ws_size,
                              hipStream_t stream) {
    const float* x    = (const float*)d_in[0];
    const int*   nidx = (const int*)d_in[1];
    float*       out  = (float*)d_out;

    if (ws_size >= XH_BYTES && d_ws != nullptr) {
        u4* xH = (u4*)d_ws;
        icopool_pack_h<<<dim3(IBX, NG), dim3(TPB), 0, stream>>>(x, xH);
        icopool_gather_h2<<<dim3(BLOCKS2), dim3(TPB), 0, stream>>>((const h8*)xH, nidx, out);
    } else {
        icopool_gather<<<dim3(BLOCKS_V1), dim3(TPB), 0, stream>>>(x, nidx, out);
    }
}

// Round 8
// 562.499 us; speedup vs baseline: 1.0307x; 1.0307x over previous
//
#include <hip/hip_runtime.h>

// IcoPool: out[b,f,v] = mean_{k<7} x[b,f,idx[v,k]]
// x: (8, 64, 163842) f32, idx: (40962, 7) int32, out: (8, 64, 40962) f32
//
// v2-v7 history: interleaved fp16 slab (64B entry = 32 rows of one vertex),
//   quad-cooperative full-line gathers, L2/L3 window blocking. v7 (deeper
//   MLP + idx amortization + wider pass-1 reads) was NULL -> not request-
//   depth limited; limiter is fill latency.
// v8: slab (168 MB) fits the 256 MB die-level Infinity Cache, but v7 pushed
//   it out: nt-stores on slab writes + 335 MB of x reads polluting L3.
//   Fix: x reads are nontemporal LOADS (read-once), slab stores are REGULAR
//   (let L3 keep them), out stores stay nt (don't evict slab during gather).
//   Pass-2 fills should become L3 hits (~350 cy, not ~700) -> ~2x fill rate.

typedef float    f4 __attribute__((ext_vector_type(4)));
typedef float    f8 __attribute__((ext_vector_type(8)));
typedef _Float16 h8 __attribute__((ext_vector_type(8)));
typedef unsigned int u4 __attribute__((ext_vector_type(4)));

constexpr int B = 8, F = 64, V_IN = 163842, V_OUT = 40962, K = 7;
constexpr int ROWS = B * F;                        // 512
constexpr int RG   = 32;                           // rows per entry (64 B fp16)
constexpr int NG   = ROWS / RG;                    // 16 groups
constexpr int TPB  = 256;
constexpr int GPX  = NG / 8;                       // 2 groups per XCD
// pass 1
constexpr int CPB  = 256;                          // columns per block
constexpr int IBX  = (V_IN + CPB - 1) / CPB;       // 641
constexpr int LSH  = 34;                           // LDS halves per column (32+pad)
// pass 2
constexpr int VPB  = 64;                           // v per block (4 lanes each)
constexpr int VB   = (V_OUT + VPB - 1) / VPB;      // 641
constexpr int BLOCKS2 = 8 * VB;                    // 5128 (both groups per block)
constexpr size_t XH_BYTES = (size_t)NG * V_IN * 64; // 167.8 MB

// ---- pass 1: transpose-pack 32 f32 rows -> 64B fp16 entries, via LDS ----
__global__ __launch_bounds__(TPB) void icopool_pack_h(
    const float* __restrict__ x, u4* __restrict__ xH)
{
    __shared__ _Float16 tile[CPB * LSH];           // 17408 B
    const int g  = blockIdx.y;
    const int c0 = blockIdx.x * CPB;
    const int t  = threadIdx.x;
    const int r  = t >> 3;                         // 0..31
    const int ci = t & 7;

    const float* xr = x + (size_t)(g * RG + r) * V_IN;
    if (c0 + CPB <= V_IN) {
        #pragma unroll
        for (int it = 0; it < 4; ++it) {
            const int c8 = ci * 8 + it * 64;
            const f4 v0 = __builtin_nontemporal_load((const f4*)(xr + c0 + c8));
            const f4 v1 = __builtin_nontemporal_load((const f4*)(xr + c0 + c8 + 4));
            tile[(c8 + 0) * LSH + r] = (_Float16)v0.x;
            tile[(c8 + 1) * LSH + r] = (_Float16)v0.y;
            tile[(c8 + 2) * LSH + r] = (_Float16)v0.z;
            tile[(c8 + 3) * LSH + r] = (_Float16)v0.w;
            tile[(c8 + 4) * LSH + r] = (_Float16)v1.x;
            tile[(c8 + 5) * LSH + r] = (_Float16)v1.y;
            tile[(c8 + 6) * LSH + r] = (_Float16)v1.z;
            tile[(c8 + 7) * LSH + r] = (_Float16)v1.w;
        }
    } else {
        for (int it = 0; it < 4; ++it) {
            const int c8 = ci * 8 + it * 64;
            for (int jj = 0; jj < 8; ++jj) {
                const int c = c0 + c8 + jj;
                tile[(c8 + jj) * LSH + r] =
                    (c < V_IN) ? (_Float16)xr[c] : (_Float16)0.0f;
            }
        }
    }
    __syncthreads();

    const unsigned int* ld = (const unsigned int*)tile;  // dword view (17/col)
    u4* dst = xH + ((size_t)g * V_IN + c0) * 4;
    #pragma unroll
    for (int it = 0; it < 4; ++it) {
        const int c   = (t >> 2) + it * 64;        // 0..255
        const int sub = t & 3;
        if (c0 + c < V_IN) {
            u4 w;
            w.x = ld[c * 17 + sub * 4 + 0];
            w.y = ld[c * 17 + sub * 4 + 1];
            w.z = ld[c * 17 + sub * 4 + 2];
            w.w = ld[c * 17 + sub * 4 + 3];
            dst[(size_t)c * 4 + sub] = w;          // REGULAR store: stay in L3
        }
    }
}

// ---- pass 2: quad-cooperative fp16 gather, both XCD groups per block ----
__global__ __launch_bounds__(TPB) void icopool_gather_h2(
    const h8* __restrict__ xH,
    const int* __restrict__ nidx,
    float*     __restrict__ out)
{
    const int b   = blockIdx.x;
    const int xcd = b & 7;               // HW round-robin XCD assignment
    const int vb  = b >> 3;              // v-block
    const int sub = threadIdx.x & 3;
    const int lv  = threadIdx.x >> 2;    // 0..63
    const int v   = vb * VPB + lv;
    if (v >= V_OUT) return;
    const int g0  = xcd * GPX;

    const int base = v * K;
    const int i0 = nidx[base + 0];
    const int i1 = nidx[base + 1];
    const int i2 = nidx[base + 2];
    const int i3 = nidx[base + 3];
    const int i4 = nidx[base + 4];
    const int i5 = nidx[base + 5];
    const int i6 = nidx[base + 6];

    const h8* s0 = xH + ((size_t)g0 * V_IN) * 4 + sub;
    const h8* s1 = s0 + (size_t)V_IN * 4;

    const h8 a0 = s0[(size_t)i0 * 4];
    const h8 a1 = s0[(size_t)i1 * 4];
    const h8 a2 = s0[(size_t)i2 * 4];
    const h8 a3 = s0[(size_t)i3 * 4];
    const h8 a4 = s0[(size_t)i4 * 4];
    const h8 a5 = s0[(size_t)i5 * 4];
    const h8 a6 = s0[(size_t)i6 * 4];
    const h8 b0 = s1[(size_t)i0 * 4];
    const h8 b1 = s1[(size_t)i1 * 4];
    const h8 b2 = s1[(size_t)i2 * 4];
    const h8 b3 = s1[(size_t)i3 * 4];
    const h8 b4 = s1[(size_t)i4 * 4];
    const h8 b5 = s1[(size_t)i5 * 4];
    const h8 b6 = s1[(size_t)i6 * 4];

    f8 acc0 = __builtin_convertvector(a0, f8);
    acc0 += __builtin_convertvector(a1, f8);
    acc0 += __builtin_convertvector(a2, f8);
    acc0 += __builtin_convertvector(a3, f8);
    acc0 += __builtin_convertvector(a4, f8);
    acc0 += __builtin_convertvector(a5, f8);
    acc0 += __builtin_convertvector(a6, f8);
    acc0 *= (1.0f / 7.0f);
    f8 acc1 = __builtin_convertvector(b0, f8);
    acc1 += __builtin_convertvector(b1, f8);
    acc1 += __builtin_convertvector(b2, f8);
    acc1 += __builtin_convertvector(b3, f8);
    acc1 += __builtin_convertvector(b4, f8);
    acc1 += __builtin_convertvector(b5, f8);
    acc1 += __builtin_convertvector(b6, f8);
    acc1 *= (1.0f / 7.0f);

    float* o0 = out + (size_t)(g0 * RG + sub * 8) * V_OUT + v;
    float* o1 = o0 + (size_t)RG * V_OUT;
    #pragma unroll
    for (int rr = 0; rr < 8; ++rr) {
        __builtin_nontemporal_store(acc0[rr], o0 + (size_t)rr * V_OUT);
        __builtin_nontemporal_store(acc1[rr], o1 + (size_t)rr * V_OUT);
    }
}

// ---------------- fallback (v1): direct gather, no workspace ----------------
constexpr int RPB  = 2;
constexpr int RGS  = ROWS / RPB;
constexpr int RG_PER_XCD = RGS / 8;
constexpr int VB1  = (V_OUT + TPB - 1) / TPB;
constexpr int BLOCKS_V1  = RGS * VB1;

__global__ __launch_bounds__(TPB) void icopool_gather(
    const float* __restrict__ x,
    const int*   __restrict__ nidx,
    float*       __restrict__ out)
{
    const int b        = blockIdx.x;
    const int xcd      = b & 7;
    const int j        = b >> 3;
    const int rg_local = j / VB1;
    const int vb       = j % VB1;
    const int rg       = xcd * RG_PER_XCD + rg_local;
    const int r0       = rg * RPB;

    const int v = vb * TPB + threadIdx.x;
    if (v >= V_OUT) return;

    const int base = v * K;
    const int i0 = nidx[base + 0];
    const int i1 = nidx[base + 1];
    const int i2 = nidx[base + 2];
    const int i3 = nidx[base + 3];
    const int i4 = nidx[base + 4];
    const int i5 = nidx[base + 5];
    const int i6 = nidx[base + 6];

    #pragma unroll
    for (int r = 0; r < RPB; ++r) {
        const float* xr = x + (size_t)(r0 + r) * V_IN;
        float sum = xr[i0] + xr[i1] + xr[i2] + xr[i3] + xr[i4] + xr[i5] + xr[i6];
        __builtin_nontemporal_store(sum * (1.0f / 7.0f),
                                    out + (size_t)(r0 + r) * V_OUT + v);
    }
}

extern "C" void kernel_launch(void* const* d_in, const int* in_sizes, int n_in,
                              void* d_out, int out_size, void* d_ws, size_t ws_size,
                              hipStream_t stream) {
    const float* x    = (const float*)d_in[0];
    const int*   nidx = (const int*)d_in[1];
    float*       out  = (float*)d_out;

    if (ws_size >= XH_BYTES && d_ws != nullptr) {
        u4* xH = (u4*)d_ws;
        icopool_pack_h<<<dim3(IBX, NG), dim3(TPB), 0, stream>>>(x, xH);
        icopool_gather_h2<<<dim3(BLOCKS2), dim3(TPB), 0, stream>>>((const h8*)xH, nidx, out);
    } else {
        icopool_gather<<<dim3(BLOCKS_V1), dim3(TPB), 0, stream>>>(x, nidx, out);
    }
}